// Round 10
// baseline (303.389 us; speedup 1.0000x reference)
//
#include <hip/hip_runtime.h>
#include <math.h>

#define N_NODES 65536
#define NPG     512
#define NGRAPH  128
#define E_EDGES 524288
#define MAXDEG  64
#define NHEADS  8
#define F1      20
#define HID     128
#define D160    160
#define KSEL    256
#define NLBL    100

// prep-kernel block ranges
#define IMG_A2_ELEMS (144*168)
#define IMG_B1_ELEMS (176*136)
#define PB_ZERO 0
#define PB_A2   64
#define PB_B1   (PB_A2 + 95)
#define PB_B2   (PB_B1 + 94)
#define PB_WA1  (PB_B2 + 95)
#define PB_EST  (PB_WA1 + 63)
#define PB_TOT  (PB_EST + 7)

typedef unsigned short ushort_t;
typedef unsigned int   uint_t;
typedef unsigned long long u64;
typedef __attribute__((ext_vector_type(8))) short short8;
typedef __attribute__((ext_vector_type(4))) float f32x4;

__device__ __forceinline__ float lrelu(float x){ return x > 0.f ? x : 0.2f*x; }
__device__ __forceinline__ ushort_t f2bf(float f){
    uint_t u = __float_as_uint(f);
    return (ushort_t)((u + 0x7FFFu + ((u >> 16) & 1u)) >> 16);
}
__device__ __forceinline__ float bf2f(ushort_t u){ return __uint_as_float(((uint_t)u) << 16); }
__device__ __forceinline__ float bflo(uint_t v){ return __uint_as_float(v << 16); }
__device__ __forceinline__ float bfhi(uint_t v){ return __uint_as_float(v & 0xFFFF0000u); }
__device__ __forceinline__ int xswz(int bid, int nblocks){
    return (bid & 7) * (nblocks >> 3) + (bid >> 3);
}

// sortable composite: desc score, tie -> asc idx
__device__ __forceinline__ u64 comp_make(float s, int idx){
    uint_t u = __float_as_uint(s);
    u ^= (u & 0x80000000u) ? 0xFFFFFFFFu : 0x80000000u;
    return ((u64)u << 32) | (u64)(511 - idx);
}
__device__ __forceinline__ float comp_score(u64 c){
    uint_t u = (uint_t)(c >> 32);
    u ^= (u & 0x80000000u) ? 0x80000000u : 0xFFFFFFFFu;
    return __uint_as_float(u);
}
__device__ __forceinline__ int comp_idx(u64 c){ return 511 - (int)(c & 0x1FFu); }
__device__ __forceinline__ u64 shfl_xor_u64(u64 x, int m){
    uint_t lo = __shfl_xor((uint_t)x, m);
    uint_t hi = __shfl_xor((uint_t)(x >> 32), m);
    return ((u64)hi << 32) | lo;
}

// ---------------- mega-prep: zero deg + 3 GEMM weight images + A1 tables ----------------
__global__ void k_prep(const float* __restrict__ Wa1, const float* __restrict__ as1,
                       const float* __restrict__ ad1,
                       const float* __restrict__ Wa2, const float* __restrict__ as2,
                       const float* __restrict__ ad2,
                       const float* __restrict__ Wb1, const float* __restrict__ asb1,
                       const float* __restrict__ adb1,
                       const float* __restrict__ Wb2, const float* __restrict__ asb2,
                       const float* __restrict__ adb2,
                       int* __restrict__ deg,
                       ushort_t* __restrict__ imgA2, ushort_t* __restrict__ imgB1,
                       ushort_t* __restrict__ imgB2,
                       ushort_t* __restrict__ Wbf, float* __restrict__ esT,
                       float* __restrict__ edT){
    int bid = blockIdx.x, tid = threadIdx.x;
    if(bid < PB_A2){
        ((uint4*)deg)[(bid - PB_ZERO)*256 + tid] = (uint4){0,0,0,0};
    } else if(bid < PB_B1 || (bid >= PB_B2 && bid < PB_WA1)){
        bool isB2 = (bid >= PB_B2);
        int j = (bid - (isB2 ? PB_B2 : PB_A2))*256 + tid;
        if(j < IMG_A2_ELEMS){
            const float* W  = isB2 ? Wb2 : Wa2;
            const float* as = isB2 ? asb2 : as2;
            const float* ad = isB2 ? adb2 : ad2;
            int n = j / 168, k = j - n*168;
            float v = 0.f;
            if(k < 160){
                if(n < 128) v = W[k*128 + n];
                else if(n < 130){
                    const float* av = (n == 128) ? as : ad;
                    float s = 0.f;
                    for(int c=0; c<128; ++c) s += W[k*128 + c]*av[c];
                    v = s;
                }
            }
            (isB2 ? imgB2 : imgA2)[j] = f2bf(v);
        }
    } else if(bid < PB_B2){
        int j = (bid - PB_B1)*256 + tid;
        if(j < IMG_B1_ELEMS){
            int n = j / 136, k = j - n*136;
            float v = 0.f;
            if(k < 128){
                if(n < 160) v = Wb1[k*160 + n];
                else {
                    int j2 = n - 160, h = j2 & 7;
                    const float* av = ((j2 < 8) ? asb1 : adb1) + h*F1;
                    const float* wr = Wb1 + k*160 + h*F1;
                    float s = 0.f;
                    #pragma unroll
                    for(int f=0; f<F1; ++f) s += wr[f]*av[f];
                    v = s;
                }
            }
            imgB1[j] = f2bf(v);
        }
    } else if(bid < PB_EST){
        int j = (bid - PB_WA1)*256 + tid;
        if(j < NLBL*D160) Wbf[j] = f2bf(Wa1[j]);
    } else {
        int t = (bid - PB_EST)*256 + tid;
        if(t < NLBL*16){
            int lbl = t >> 4, j = t & 15, h = j & 7;
            const float* av = ((j < 8) ? as1 : ad1) + h*F1;
            const float* wr = Wa1 + lbl*D160 + h*F1;
            float s = 0.f;
            #pragma unroll
            for(int f=0; f<F1; ++f) s += wr[f]*av[f];
            if(j < 8) esT[lbl*8 + h] = s;
            else      edT[lbl*8 + h] = s;
        }
    }
}

// ---------------- ELL adjacency build (dst -> list of src) ----------------
__global__ void k_build_ell(const int* __restrict__ src, const int* __restrict__ dst,
                            int* __restrict__ deg, int* __restrict__ ell){
    int blk = xswz(blockIdx.x, E_EDGES/256);
    int e = blk*blockDim.x + threadIdx.x;
    int d = dst[e];
    int p = atomicAdd(&deg[d], 1);
    if(p < MAXDEG) ell[d*MAXDEG + p] = src[e];
}

// ---------------- layer A fused z-gen + 8-head attention (LDS label table) ----------------
__global__ __launch_bounds__(256) void k_attn8_a(const int* __restrict__ x,
        const int* __restrict__ deg, const int* __restrict__ ell,
        const ushort_t* __restrict__ Wbf, const float* __restrict__ esT,
        const float* __restrict__ edT, const float* __restrict__ bias,
        ushort_t* __restrict__ out){
    __shared__ __align__(16) ushort_t Wl[NLBL*D160];
    __shared__ float esL[NLBL*8], edL[NLBL*8];
    int tid = threadIdx.x;
    for(int i = tid; i < NLBL*D160/8; i += 256)
        ((uint4*)Wl)[i] = ((const uint4*)Wbf)[i];
    for(int i = tid; i < NLBL*8; i += 256){ esL[i] = esT[i]; edL[i] = edT[i]; }
    __syncthreads();
    int blk = xswz(blockIdx.x, N_NODES*NHEADS/256);
    int t = blk*256 + tid;
    int n = t >> 3, h = t & 7;
    int dg = deg[n]; if(dg > MAXDEG) dg = MAXDEG;
    int lbl = x[n];
    float edn = edL[lbl*8 + h];
    float wself = expf(lrelu(esL[lbl*8 + h] + edn));
    float den = wself;
    float acc[F1];
    {
        const uint_t* zn = (const uint_t*)Wl + lbl*80 + h*10;
        #pragma unroll
        for(int f=0; f<10; ++f){
            uint_t v = zn[f];
            acc[2*f]   = wself*bflo(v);
            acc[2*f+1] = wself*bfhi(v);
        }
    }
    const int* el = ell + n*MAXDEG;
    int i = 0;
    for(; i+2 <= dg; i += 2){
        int sa = el[i], sb = el[i+1];
        int la = x[sa], lb = x[sb];
        float wa = expf(lrelu(esL[la*8 + h] + edn));
        float wb = expf(lrelu(esL[lb*8 + h] + edn));
        den += wa + wb;
        const uint_t* za = (const uint_t*)Wl + la*80 + h*10;
        const uint_t* zb = (const uint_t*)Wl + lb*80 + h*10;
        #pragma unroll
        for(int f=0; f<10; ++f){
            uint_t va = za[f], vb = zb[f];
            acc[2*f]   += wa*bflo(va) + wb*bflo(vb);
            acc[2*f+1] += wa*bfhi(va) + wb*bfhi(vb);
        }
    }
    if(i < dg){
        int sa = el[i];
        int la = x[sa];
        float wa = expf(lrelu(esL[la*8 + h] + edn));
        den += wa;
        const uint_t* za = (const uint_t*)Wl + la*80 + h*10;
        #pragma unroll
        for(int f=0; f<10; ++f){
            uint_t va = za[f];
            acc[2*f]   += wa*bflo(va);
            acc[2*f+1] += wa*bfhi(va);
        }
    }
    float inv = 1.f/(den + 1e-16f);
    uint_t* o = (uint_t*)(out + (size_t)n*D160 + h*F1);
    const float* bb = bias + h*F1;
    #pragma unroll
    for(int f=0; f<10; ++f){
        float v0 = fmaxf(acc[2*f]*inv   + bb[2*f],   0.f);
        float v1 = fmaxf(acc[2*f+1]*inv + bb[2*f+1], 0.f);
        o[f] = (uint_t)f2bf(v0) | ((uint_t)f2bf(v1) << 16);
    }
}

// ---------------- layer B 8-head attention, per-graph LDS staging ----------------
// 256 blocks = (graph, head-half). z half-tile in LDS [512][88] (176B rows: 11*s%8
// start-quad spread => near-uniform banks). Thread = node; 4 heads x 20ch in regs.
__global__ __launch_bounds__(512) void k_attn8b(const int* __restrict__ deg,
        const int* __restrict__ ell, const ushort_t* __restrict__ z8,
        const float* __restrict__ es8, const float* __restrict__ ed8,
        const float* __restrict__ bias, ushort_t* __restrict__ out){
    __shared__ __align__(16) ushort_t zl[512*88];
    __shared__ __align__(16) float4 esl[512];
    __shared__ __align__(16) float4 edl[512];
    int tid = threadIdx.x;
    int blk = xswz(blockIdx.x, NGRAPH*2);
    int g = blk >> 1, hg = blk & 1;
    int base = g*NPG;
    for(int idx = tid; idx < 512*10; idx += 512){
        int row = idx/10, q = idx - (idx/10)*10;
        uint4 v = *(const uint4*)(z8 + (size_t)(base+row)*D160 + hg*80 + q*8);
        *(uint4*)(zl + row*88 + q*8) = v;
    }
    esl[tid] = *(const float4*)(es8 + (size_t)(base+tid)*8 + hg*4);
    edl[tid] = *(const float4*)(ed8 + (size_t)(base+tid)*8 + hg*4);
    __syncthreads();
    int n = tid;
    int dg = deg[base+n]; if(dg > MAXDEG) dg = MAXDEG;
    const int* el = ell + (size_t)(base+n)*MAXDEG;
    float4 edn = edl[n];
    float4 esn = esl[n];
    float w0 = expf(lrelu(esn.x + edn.x));
    float w1 = expf(lrelu(esn.y + edn.y));
    float w2 = expf(lrelu(esn.z + edn.z));
    float w3 = expf(lrelu(esn.w + edn.w));
    float den0 = w0, den1 = w1, den2 = w2, den3 = w3;
    float acc[80];
    #pragma unroll
    for(int q=0; q<10; ++q){
        uint4 v = *(const uint4*)(zl + n*88 + q*8);
        const uint_t* vu = (const uint_t*)&v;
        #pragma unroll
        for(int r=0; r<4; ++r){
            int ch = q*8 + r*2;
            float wA = (ch < 20) ? w0 : (ch < 40) ? w1 : (ch < 60) ? w2 : w3;
            float wB = (ch+1 < 20) ? w0 : (ch+1 < 40) ? w1 : (ch+1 < 60) ? w2 : w3;
            acc[ch]   = wA*bflo(vu[r]);
            acc[ch+1] = wB*bfhi(vu[r]);
        }
    }
    for(int i=0; i<dg; ++i){
        int s = el[i] & (NPG-1);
        float4 es_s = esl[s];
        float wa0 = expf(lrelu(es_s.x + edn.x));
        float wa1 = expf(lrelu(es_s.y + edn.y));
        float wa2 = expf(lrelu(es_s.z + edn.z));
        float wa3 = expf(lrelu(es_s.w + edn.w));
        den0 += wa0; den1 += wa1; den2 += wa2; den3 += wa3;
        #pragma unroll
        for(int q=0; q<10; ++q){
            uint4 v = *(const uint4*)(zl + s*88 + q*8);
            const uint_t* vu = (const uint_t*)&v;
            #pragma unroll
            for(int r=0; r<4; ++r){
                int ch = q*8 + r*2;
                float wA = (ch < 20) ? wa0 : (ch < 40) ? wa1 : (ch < 60) ? wa2 : wa3;
                float wB = (ch+1 < 20) ? wa0 : (ch+1 < 40) ? wa1 : (ch+1 < 60) ? wa2 : wa3;
                acc[ch]   += wA*bflo(vu[r]);
                acc[ch+1] += wB*bfhi(vu[r]);
            }
        }
    }
    float inv0 = 1.f/(den0 + 1e-16f);
    float inv1 = 1.f/(den1 + 1e-16f);
    float inv2 = 1.f/(den2 + 1e-16f);
    float inv3 = 1.f/(den3 + 1e-16f);
    const float* bb = bias + hg*80;
    uint_t* o = (uint_t*)out + (size_t)(base+n)*80 + hg*40;
    #pragma unroll
    for(int q=0; q<10; ++q){
        #pragma unroll
        for(int r=0; r<4; ++r){
            int ch = q*8 + r*2;
            float iA = (ch < 20) ? inv0 : (ch < 40) ? inv1 : (ch < 60) ? inv2 : inv3;
            float iB = (ch+1 < 20) ? inv0 : (ch+1 < 40) ? inv1 : (ch+1 < 60) ? inv2 : inv3;
            float v0 = fmaxf(acc[ch]*iA   + bb[ch],   0.f);
            float v1 = fmaxf(acc[ch+1]*iB + bb[ch+1], 0.f);
            o[q*4 + r] = (uint_t)f2bf(v0) | ((uint_t)f2bf(v1) << 16);
        }
    }
}

// ---------------- MFMA GEMM from prebuilt bf16 image; es/ed from last fragment ----------
template<int IN, int OUTC, int OUTIMG, bool ESED8>
__global__ __launch_bounds__(256) void k_gemm2(const ushort_t* __restrict__ Wimg,
                                               const ushort_t* __restrict__ A,
                                               ushort_t* __restrict__ C,
                                               float* __restrict__ oa,
                                               float* __restrict__ ob){
    constexpr int LDW = IN + 8;
    constexpr int NT = OUTIMG/16;
    constexpr int NC = OUTC/16;
    constexpr int KS = IN/32;
    constexpr int ELEMS = OUTIMG*LDW;
    __shared__ __align__(16) ushort_t Wt[ELEMS];
    int tid = threadIdx.x;
    int blk = xswz(blockIdx.x, N_NODES/64);
    int wave = tid >> 6, lane = tid & 63;
    int col16 = lane & 15;
    int kq = (lane >> 4) * 8;
    int row = blk*64 + wave*16 + col16;
    const ushort_t* Ar = A + (size_t)row*IN + kq;
    short8 afr[KS];
    #pragma unroll
    for(int ks=0; ks<KS; ++ks)
        afr[ks] = *reinterpret_cast<const short8*>(Ar + ks*32);
    for(int i = tid; i < ELEMS/8; i += 256)
        ((uint4*)Wt)[i] = ((const uint4*)Wimg)[i];
    __syncthreads();
    f32x4 acc[NT];
    #pragma unroll
    for(int c=0;c<NT;++c) acc[c] = (f32x4){0.f,0.f,0.f,0.f};
    #pragma unroll
    for(int ks=0; ks<KS; ++ks){
        #pragma unroll
        for(int c=0;c<NT;++c){
            short8 bf = *reinterpret_cast<const short8*>(&Wt[(c*16 + col16)*LDW + ks*32 + kq]);
            acc[c] = __builtin_amdgcn_mfma_f32_16x16x32_bf16(afr[ks], bf, acc[c], 0, 0, 0);
        }
    }
    int rbase = blk*64 + wave*16 + (lane >> 4)*4;
    #pragma unroll
    for(int c=0;c<NC;++c){
        #pragma unroll
        for(int r=0;r<4;++r){
            C[(size_t)(rbase + r)*OUTC + c*16 + col16] = f2bf(acc[c][r]);
        }
    }
    if(ESED8){
        #pragma unroll
        for(int r=0;r<4;++r){
            float v = acc[NT-1][r];
            if(col16 < 8) oa[(size_t)(rbase + r)*8 + col16] = v;
            else          ob[(size_t)(rbase + r)*8 + (col16 - 8)] = v;
        }
    } else {
        if(col16 == 0){
            #pragma unroll
            for(int r=0;r<4;++r) oa[rbase + r] = acc[NT-1][r];
        }
        if(col16 == 1){
            #pragma unroll
            for(int r=0;r<4;++r) ob[rbase + r] = acc[NT-1][r];
        }
    }
}

// ---------------- 1-head attention, per-graph LDS staging (graph x channel-half) ------
// 256 blocks, 512 threads. Wave processes 2 nodes (half-wave each, lane=ch dword).
// DOT: per-half partial dots -> plane cc of oa/ob (summed in k_score).
template<bool DOT>
__global__ __launch_bounds__(512) void k_attn1L(const int* __restrict__ deg,
        const int* __restrict__ ell, const ushort_t* __restrict__ Z,
        const float* __restrict__ es, const float* __restrict__ ed,
        const float* __restrict__ bias, ushort_t* __restrict__ out,
        const float* __restrict__ wa, const float* __restrict__ wb,
        float* __restrict__ oa, float* __restrict__ ob){
    __shared__ __align__(16) ushort_t zl[512*72];
    __shared__ float esl[512], edl[512];
    int tid = threadIdx.x;
    int blk = xswz(blockIdx.x, NGRAPH*2);
    int g = blk >> 1, cc = blk & 1;
    int base = g*NPG;
    for(int idx = tid; idx < 512*8; idx += 512){
        int row = idx >> 3, q = idx & 7;
        *(uint4*)(zl + row*72 + q*8) =
            *(const uint4*)(Z + (size_t)(base+row)*HID + cc*64 + q*8);
    }
    esl[tid] = es[base+tid];
    edl[tid] = ed[base+tid];
    __syncthreads();
    int wv = tid >> 6, l = tid & 63;
    int half = l >> 5, lc = l & 31;
    for(int it=0; it<32; ++it){
        int n = wv*64 + it*2 + half;
        int dgn = deg[base+n]; if(dgn > MAXDEG) dgn = MAXDEG;
        float edn = edl[n];
        float wself = expf(lrelu(esl[n] + edn));
        float den = wself;
        uint_t zn = *(const uint_t*)(zl + n*72 + lc*2);
        float a0 = wself*bflo(zn);
        float a1 = wself*bfhi(zn);
        const int* el = ell + (size_t)(base+n)*MAXDEG;
        for(int i=0; i<dgn; ++i){
            int s = el[i] & (NPG-1);
            float w = expf(lrelu(esl[s] + edn));
            den += w;
            uint_t zv = *(const uint_t*)(zl + s*72 + lc*2);
            a0 += w*bflo(zv);
            a1 += w*bfhi(zv);
        }
        float inv = 1.f/(den + 1e-16f);
        float2 bb = ((const float2*)(bias + cc*64))[lc];
        float r0 = fmaxf(a0*inv + bb.x, 0.f);
        float r1 = fmaxf(a1*inv + bb.y, 0.f);
        ((uint_t*)out)[(size_t)(base+n)*64 + cc*32 + lc] =
            (uint_t)f2bf(r0) | ((uint_t)f2bf(r1) << 16);
        if(DOT){
            float2 a2 = ((const float2*)(wa + cc*64))[lc];
            float2 b2 = ((const float2*)(wb + cc*64))[lc];
            float pa = r0*a2.x + r1*a2.y;
            float pb = r0*b2.x + r1*b2.y;
            for(int o=16; o>0; o>>=1){ pa += __shfl_xor(pa,o); pb += __shfl_xor(pb,o); }
            if(lc == 0){
                oa[cc*N_NODES + base + n] = pa;
                ob[cc*N_NODES + base + n] = pb;
            }
        }
    }
}

// ---------------- pooling score (sums the two channel-half planes) ----------------
__global__ void k_score(const int* __restrict__ deg, const int* __restrict__ ell,
                        const float* __restrict__ y2, const float* __restrict__ r2,
                        const float* __restrict__ bpool, float* __restrict__ score){
    int blk = xswz(blockIdx.x, N_NODES/256);
    int n = blk*blockDim.x + threadIdx.x;
    int dg = deg[n]; if(dg > MAXDEG) dg = MAXDEG;
    float s = r2[n] + r2[N_NODES + n] + bpool[0];
    const int* el = ell + n*MAXDEG;
    int i = 0;
    for(; i+4 <= dg; i += 4){
        int e0 = el[i], e1 = el[i+1], e2 = el[i+2], e3 = el[i+3];
        float y0 = y2[e0] + y2[N_NODES + e0];
        float y1 = y2[e1] + y2[N_NODES + e1];
        float ya = y2[e2] + y2[N_NODES + e2];
        float yb = y2[e3] + y2[N_NODES + e3];
        s += (y0 + y1) + (ya + yb);
    }
    for(; i < dg; ++i){
        int e0 = el[i];
        s += y2[e0] + y2[N_NODES + e0];
    }
    score[n] = tanhf(s);
}

// ---------------- per-graph top-k: single-wave register bitonic + parallel pool ----------------
__global__ __launch_bounds__(512) void k_topk_pool(const float* __restrict__ score,
                                                   const ushort_t* __restrict__ H,
                                                   float* __restrict__ pooled,
                                                   float* __restrict__ perm_f,
                                                   float* __restrict__ sv,
                                                   float* __restrict__ batch_f){
    __shared__ int   sidx[KSEL];
    __shared__ float sval[KSEL];
    __shared__ float pmax[512];
    int g = xswz(blockIdx.x, NGRAPH);
    int base = g*NPG;
    int t = threadIdx.x;
    if(t < 64){
        int l = t;
        u64 v[8];
        #pragma unroll
        for(int r=0;r<8;++r){
            int i = r*64 + l;
            v[r] = comp_make(score[base + i], i);
        }
        #pragma unroll
        for(int kk=1; kk<=9; ++kk){
            int k = 1 << kk;
            #pragma unroll
            for(int jj=kk-1; jj>=0; --jj){
                int j = 1 << jj;
                if(j < 64){
                    bool lower = (l & j) == 0;
                    #pragma unroll
                    for(int r=0;r<8;++r){
                        int i = r*64 + l;
                        u64 p = shfl_xor_u64(v[r], j);
                        bool desc = (i & k) == 0;
                        u64 mx = v[r] > p ? v[r] : p;
                        u64 mn = v[r] > p ? p : v[r];
                        v[r] = (lower == desc) ? mx : mn;
                    }
                } else {
                    int jr = j >> 6;
                    #pragma unroll
                    for(int r=0;r<8;++r){
                        if((r & jr) == 0){
                            int rp = r | jr;
                            int i = r*64 + l;
                            bool desc = (i & k) == 0;
                            u64 a = v[r], b = v[rp];
                            u64 mx = a > b ? a : b;
                            u64 mn = a > b ? b : a;
                            v[r]  = desc ? mx : mn;
                            v[rp] = desc ? mn : mx;
                        }
                    }
                }
            }
        }
        #pragma unroll
        for(int r=0;r<4;++r){
            int i = r*64 + l;
            int idx = comp_idx(v[r]);
            float s = comp_score(v[r]);
            perm_f[g*KSEL + i]  = (float)(base + idx);
            sv[g*KSEL + i]      = s;
            batch_f[g*KSEL + i] = (float)g;
            sidx[i] = idx; sval[i] = s;
        }
    }
    __syncthreads();
    int c = t & 127, kc = t >> 7;
    float mx = -1e30f;
    for(int kk = kc*64; kk < kc*64 + 64; ++kk){
        mx = fmaxf(mx, bf2f(H[(size_t)(base + sidx[kk])*HID + c]) * sval[kk]);
    }
    pmax[t] = mx;
    __syncthreads();
    if(t < HID){
        pooled[g*HID + t] = fmaxf(fmaxf(pmax[t], pmax[t+128]),
                                  fmaxf(pmax[t+256], pmax[t+384]));
    }
}

extern "C" void kernel_launch(void* const* d_in, const int* in_sizes, int n_in,
                              void* d_out, int out_size, void* d_ws, size_t ws_size,
                              hipStream_t stream) {
    const int*   x       = (const int*)  d_in[0];
    const int*   eidx    = (const int*)  d_in[1];
    const float* W_a1    = (const float*)d_in[3];
    const float* asrc_a1 = (const float*)d_in[4];
    const float* adst_a1 = (const float*)d_in[5];
    const float* b_a1    = (const float*)d_in[6];
    const float* W_a2    = (const float*)d_in[7];
    const float* asrc_a2 = (const float*)d_in[8];
    const float* adst_a2 = (const float*)d_in[9];
    const float* b_a2    = (const float*)d_in[10];
    const float* W_b1    = (const float*)d_in[11];
    const float* asrc_b1 = (const float*)d_in[12];
    const float* adst_b1 = (const float*)d_in[13];
    const float* b_b1    = (const float*)d_in[14];
    const float* W_b2    = (const float*)d_in[15];
    const float* asrc_b2 = (const float*)d_in[16];
    const float* adst_b2 = (const float*)d_in[17];
    const float* b_b2    = (const float*)d_in[18];
    const float* w_rel   = (const float*)d_in[19];
    const float* w_root  = (const float*)d_in[20];
    const float* b_pool  = (const float*)d_in[21];

    const int* e_src = eidx;
    const int* e_dst = eidx + E_EDGES;

    char* ws = (char*)d_ws;
    size_t off = 0;
    auto alloc = [&](size_t bytes)->char*{
        char* p = ws + off;
        off += (bytes + 255) & ~(size_t)255;
        return p;
    };
    int*      deg    = (int*)     alloc((size_t)N_NODES*4);
    int*      ell    = (int*)     alloc((size_t)N_NODES*MAXDEG*4);
    ushort_t* z8     = (ushort_t*)alloc((size_t)N_NODES*D160*2);
    ushort_t* h8     = (ushort_t*)alloc((size_t)N_NODES*D160*2);
    ushort_t* zc     = (ushort_t*)alloc((size_t)N_NODES*HID*2);
    ushort_t* hmid   = (ushort_t*)alloc((size_t)N_NODES*HID*2);
    ushort_t* hfin   = (ushort_t*)alloc((size_t)N_NODES*HID*2);
    float*    es8    = (float*)   alloc((size_t)N_NODES*NHEADS*4);
    float*    ed8    = (float*)   alloc((size_t)N_NODES*NHEADS*4);
    float*    es1    = (float*)   alloc((size_t)N_NODES*4);
    float*    ed1    = (float*)   alloc((size_t)N_NODES*4);
    float*    yrel2  = (float*)   alloc((size_t)N_NODES*2*4);
    float*    rroot2 = (float*)   alloc((size_t)N_NODES*2*4);
    float*    score  = (float*)   alloc((size_t)N_NODES*4);
    ushort_t* Wbf    = (ushort_t*)alloc((size_t)NLBL*D160*2);
    float*    esT    = (float*)   alloc((size_t)NLBL*8*4);
    float*    edT    = (float*)   alloc((size_t)NLBL*8*4);
    ushort_t* imgA2  = (ushort_t*)alloc((size_t)IMG_A2_ELEMS*2);
    ushort_t* imgB1  = (ushort_t*)alloc((size_t)IMG_B1_ELEMS*2);
    ushort_t* imgB2  = (ushort_t*)alloc((size_t)IMG_A2_ELEMS*2);
    (void)ws_size; (void)n_in; (void)in_sizes; (void)out_size;

    float* out      = (float*)d_out;
    float* pooled   = out;
    float* perm_f   = out + NGRAPH*HID;
    float* sv       = perm_f + NGRAPH*KSEL;
    float* batch_f  = sv + NGRAPH*KSEL;

    k_prep<<<PB_TOT, 256, 0, stream>>>(W_a1, asrc_a1, adst_a1,
                                       W_a2, asrc_a2, adst_a2,
                                       W_b1, asrc_b1, adst_b1,
                                       W_b2, asrc_b2, adst_b2,
                                       deg, imgA2, imgB1, imgB2, Wbf, esT, edT);
    k_build_ell<<<E_EDGES/256, 256, 0, stream>>>(e_src, e_dst, deg, ell);

    // ---- GATNet A, conv1: fused table-attention ----
    k_attn8_a<<<N_NODES*NHEADS/256, 256, 0, stream>>>(x, deg, ell, Wbf, esT, edT, b_a1, h8);

    // ---- GATNet A, conv2 (160 -> 128) + es1/ed1 via extra image cols ----
    k_gemm2<D160, HID, 144, false><<<N_NODES/64, 256, 0, stream>>>(imgA2, h8, zc, es1, ed1);
    k_attn1L<false><<<NGRAPH*2, 512, 0, stream>>>(deg, ell, zc, es1, ed1, b_a2, hmid,
                                                  nullptr, nullptr, nullptr, nullptr);

    // ---- GATNet B, conv1 (128 -> 20x8) + es8/ed8 via extra image cols ----
    k_gemm2<HID, D160, 176, true><<<N_NODES/64, 256, 0, stream>>>(imgB1, hmid, z8, es8, ed8);
    k_attn8b<<<NGRAPH*2, 512, 0, stream>>>(deg, ell, z8, es8, ed8, b_b1, h8);

    // ---- GATNet B, conv2 (160 -> 128) + es1/ed1 via extra image cols ----
    k_gemm2<D160, HID, 144, false><<<N_NODES/64, 256, 0, stream>>>(imgB2, h8, zc, es1, ed1);
    // final attention (bf16 out) + per-half pooling dots
    k_attn1L<true><<<NGRAPH*2, 512, 0, stream>>>(deg, ell, zc, es1, ed1, b_b2, hfin,
                                                 w_rel, w_root, yrel2, rroot2);

    // ---- SAGPooling ----
    k_score<<<N_NODES/256, 256, 0, stream>>>(deg, ell, yrel2, rroot2, b_pool, score);
    k_topk_pool<<<NGRAPH, NPG, 0, stream>>>(score, hfin, pooled, perm_f, sv, batch_f);
}

// Round 11
// 226.202 us; speedup vs baseline: 1.3412x; 1.3412x over previous
//
#include <hip/hip_runtime.h>
#include <math.h>

#define N_NODES 65536
#define NPG     512
#define NGRAPH  128
#define E_EDGES 524288
#define MAXDEG  64
#define NHEADS  8
#define F1      20
#define HID     128
#define D160    160
#define KSEL    256
#define NLBL    100

// prep-kernel block ranges
#define IMG_A2_ELEMS (144*168)
#define IMG_B1_ELEMS (176*136)
#define PB_ZERO 0
#define PB_A2   64
#define PB_B1   (PB_A2 + 95)
#define PB_B2   (PB_B1 + 94)
#define PB_WA1  (PB_B2 + 95)
#define PB_EST  (PB_WA1 + 63)
#define PB_TOT  (PB_EST + 7)

typedef unsigned short ushort_t;
typedef unsigned int   uint_t;
typedef unsigned long long u64;
typedef __attribute__((ext_vector_type(8))) short short8;
typedef __attribute__((ext_vector_type(4))) float f32x4;

__device__ __forceinline__ float lrelu(float x){ return x > 0.f ? x : 0.2f*x; }
__device__ __forceinline__ ushort_t f2bf(float f){
    uint_t u = __float_as_uint(f);
    return (ushort_t)((u + 0x7FFFu + ((u >> 16) & 1u)) >> 16);
}
__device__ __forceinline__ float bf2f(ushort_t u){ return __uint_as_float(((uint_t)u) << 16); }
__device__ __forceinline__ float bflo(uint_t v){ return __uint_as_float(v << 16); }
__device__ __forceinline__ float bfhi(uint_t v){ return __uint_as_float(v & 0xFFFF0000u); }
__device__ __forceinline__ int xswz(int bid, int nblocks){
    return (bid & 7) * (nblocks >> 3) + (bid >> 3);
}
__device__ __forceinline__ float rdlanef(float v, int i){
    return __uint_as_float((uint_t)__builtin_amdgcn_readlane(__float_as_int(v), i));
}

// sortable composite: desc score, tie -> asc idx
__device__ __forceinline__ u64 comp_make(float s, int idx){
    uint_t u = __float_as_uint(s);
    u ^= (u & 0x80000000u) ? 0xFFFFFFFFu : 0x80000000u;
    return ((u64)u << 32) | (u64)(511 - idx);
}
__device__ __forceinline__ float comp_score(u64 c){
    uint_t u = (uint_t)(c >> 32);
    u ^= (u & 0x80000000u) ? 0x80000000u : 0xFFFFFFFFu;
    return __uint_as_float(u);
}
__device__ __forceinline__ int comp_idx(u64 c){ return 511 - (int)(c & 0x1FFu); }
__device__ __forceinline__ u64 shfl_xor_u64(u64 x, int m){
    uint_t lo = __shfl_xor((uint_t)x, m);
    uint_t hi = __shfl_xor((uint_t)(x >> 32), m);
    return ((u64)hi << 32) | lo;
}

// ---------------- mega-prep: zero deg + 3 GEMM weight images + A1 tables ----------------
__global__ void k_prep(const float* __restrict__ Wa1, const float* __restrict__ as1,
                       const float* __restrict__ ad1,
                       const float* __restrict__ Wa2, const float* __restrict__ as2,
                       const float* __restrict__ ad2,
                       const float* __restrict__ Wb1, const float* __restrict__ asb1,
                       const float* __restrict__ adb1,
                       const float* __restrict__ Wb2, const float* __restrict__ asb2,
                       const float* __restrict__ adb2,
                       int* __restrict__ deg,
                       ushort_t* __restrict__ imgA2, ushort_t* __restrict__ imgB1,
                       ushort_t* __restrict__ imgB2,
                       ushort_t* __restrict__ Wbf, float* __restrict__ esT,
                       float* __restrict__ edT){
    int bid = blockIdx.x, tid = threadIdx.x;
    if(bid < PB_A2){
        ((uint4*)deg)[(bid - PB_ZERO)*256 + tid] = (uint4){0,0,0,0};
    } else if(bid < PB_B1 || (bid >= PB_B2 && bid < PB_WA1)){
        bool isB2 = (bid >= PB_B2);
        int j = (bid - (isB2 ? PB_B2 : PB_A2))*256 + tid;
        if(j < IMG_A2_ELEMS){
            const float* W  = isB2 ? Wb2 : Wa2;
            const float* as = isB2 ? asb2 : as2;
            const float* ad = isB2 ? adb2 : ad2;
            int n = j / 168, k = j - n*168;
            float v = 0.f;
            if(k < 160){
                if(n < 128) v = W[k*128 + n];
                else if(n < 130){
                    const float* av = (n == 128) ? as : ad;
                    float s = 0.f;
                    for(int c=0; c<128; ++c) s += W[k*128 + c]*av[c];
                    v = s;
                }
            }
            (isB2 ? imgB2 : imgA2)[j] = f2bf(v);
        }
    } else if(bid < PB_B2){
        int j = (bid - PB_B1)*256 + tid;
        if(j < IMG_B1_ELEMS){
            int n = j / 136, k = j - n*136;
            float v = 0.f;
            if(k < 128){
                if(n < 160) v = Wb1[k*160 + n];
                else {
                    int j2 = n - 160, h = j2 & 7;
                    const float* av = ((j2 < 8) ? asb1 : adb1) + h*F1;
                    const float* wr = Wb1 + k*160 + h*F1;
                    float s = 0.f;
                    #pragma unroll
                    for(int f=0; f<F1; ++f) s += wr[f]*av[f];
                    v = s;
                }
            }
            imgB1[j] = f2bf(v);
        }
    } else if(bid < PB_EST){
        int j = (bid - PB_WA1)*256 + tid;
        if(j < NLBL*D160) Wbf[j] = f2bf(Wa1[j]);
    } else {
        int t = (bid - PB_EST)*256 + tid;
        if(t < NLBL*16){
            int lbl = t >> 4, j = t & 15, h = j & 7;
            const float* av = ((j < 8) ? as1 : ad1) + h*F1;
            const float* wr = Wa1 + lbl*D160 + h*F1;
            float s = 0.f;
            #pragma unroll
            for(int f=0; f<F1; ++f) s += wr[f]*av[f];
            if(j < 8) esT[lbl*8 + h] = s;
            else      edT[lbl*8 + h] = s;
        }
    }
}

// ---------------- ELL adjacency build (dst -> list of src) ----------------
__global__ void k_build_ell(const int* __restrict__ src, const int* __restrict__ dst,
                            int* __restrict__ deg, int* __restrict__ ell){
    int blk = xswz(blockIdx.x, E_EDGES/256);
    int e = blk*blockDim.x + threadIdx.x;
    int d = dst[e];
    int p = atomicAdd(&deg[d], 1);
    if(p < MAXDEG) ell[d*MAXDEG + p] = src[e];
}

// ---------------- layer A fused z-gen + 8-head attention (LDS label table) ----------------
__global__ __launch_bounds__(256) void k_attn8_a(const int* __restrict__ x,
        const int* __restrict__ deg, const int* __restrict__ ell,
        const ushort_t* __restrict__ Wbf, const float* __restrict__ esT,
        const float* __restrict__ edT, const float* __restrict__ bias,
        ushort_t* __restrict__ out){
    __shared__ __align__(16) ushort_t Wl[NLBL*D160];
    __shared__ float esL[NLBL*8], edL[NLBL*8];
    int tid = threadIdx.x;
    for(int i = tid; i < NLBL*D160/8; i += 256)
        ((uint4*)Wl)[i] = ((const uint4*)Wbf)[i];
    for(int i = tid; i < NLBL*8; i += 256){ esL[i] = esT[i]; edL[i] = edT[i]; }
    __syncthreads();
    int blk = xswz(blockIdx.x, N_NODES*NHEADS/256);
    int t = blk*256 + tid;
    int n = t >> 3, h = t & 7;
    int dg = deg[n]; if(dg > MAXDEG) dg = MAXDEG;
    int lbl = x[n];
    float edn = edL[lbl*8 + h];
    float wself = expf(lrelu(esL[lbl*8 + h] + edn));
    float den = wself;
    float acc[F1];
    {
        const uint_t* zn = (const uint_t*)Wl + lbl*80 + h*10;
        #pragma unroll
        for(int f=0; f<10; ++f){
            uint_t v = zn[f];
            acc[2*f]   = wself*bflo(v);
            acc[2*f+1] = wself*bfhi(v);
        }
    }
    const int* el = ell + n*MAXDEG;
    int i = 0;
    for(; i+2 <= dg; i += 2){
        int sa = el[i], sb = el[i+1];
        int la = x[sa], lb = x[sb];
        float wa = expf(lrelu(esL[la*8 + h] + edn));
        float wb = expf(lrelu(esL[lb*8 + h] + edn));
        den += wa + wb;
        const uint_t* za = (const uint_t*)Wl + la*80 + h*10;
        const uint_t* zb = (const uint_t*)Wl + lb*80 + h*10;
        #pragma unroll
        for(int f=0; f<10; ++f){
            uint_t va = za[f], vb = zb[f];
            acc[2*f]   += wa*bflo(va) + wb*bflo(vb);
            acc[2*f+1] += wa*bfhi(va) + wb*bfhi(vb);
        }
    }
    if(i < dg){
        int sa = el[i];
        int la = x[sa];
        float wa = expf(lrelu(esL[la*8 + h] + edn));
        den += wa;
        const uint_t* za = (const uint_t*)Wl + la*80 + h*10;
        #pragma unroll
        for(int f=0; f<10; ++f){
            uint_t va = za[f];
            acc[2*f]   += wa*bflo(va);
            acc[2*f+1] += wa*bfhi(va);
        }
    }
    float inv = 1.f/(den + 1e-16f);
    uint_t* o = (uint_t*)(out + (size_t)n*D160 + h*F1);
    const float* bb = bias + h*F1;
    #pragma unroll
    for(int f=0; f<10; ++f){
        float v0 = fmaxf(acc[2*f]*inv   + bb[2*f],   0.f);
        float v1 = fmaxf(acc[2*f+1]*inv + bb[2*f+1], 0.f);
        o[f] = (uint_t)f2bf(v0) | ((uint_t)f2bf(v1) << 16);
    }
}

// ---------------- layer B 8-head attention, per-graph LDS staging (KEEP: ~45us win) ----
__global__ __launch_bounds__(512) void k_attn8b(const int* __restrict__ deg,
        const int* __restrict__ ell, const ushort_t* __restrict__ z8,
        const float* __restrict__ es8, const float* __restrict__ ed8,
        const float* __restrict__ bias, ushort_t* __restrict__ out){
    __shared__ __align__(16) ushort_t zl[512*88];
    __shared__ __align__(16) float4 esl[512];
    __shared__ __align__(16) float4 edl[512];
    int tid = threadIdx.x;
    int blk = xswz(blockIdx.x, NGRAPH*2);
    int g = blk >> 1, hg = blk & 1;
    int base = g*NPG;
    for(int idx = tid; idx < 512*10; idx += 512){
        int row = idx/10, q = idx - (idx/10)*10;
        uint4 v = *(const uint4*)(z8 + (size_t)(base+row)*D160 + hg*80 + q*8);
        *(uint4*)(zl + row*88 + q*8) = v;
    }
    esl[tid] = *(const float4*)(es8 + (size_t)(base+tid)*8 + hg*4);
    edl[tid] = *(const float4*)(ed8 + (size_t)(base+tid)*8 + hg*4);
    __syncthreads();
    int n = tid;
    int dg = deg[base+n]; if(dg > MAXDEG) dg = MAXDEG;
    const int* el = ell + (size_t)(base+n)*MAXDEG;
    float4 edn = edl[n];
    float4 esn = esl[n];
    float w0 = expf(lrelu(esn.x + edn.x));
    float w1 = expf(lrelu(esn.y + edn.y));
    float w2 = expf(lrelu(esn.z + edn.z));
    float w3 = expf(lrelu(esn.w + edn.w));
    float den0 = w0, den1 = w1, den2 = w2, den3 = w3;
    float acc[80];
    #pragma unroll
    for(int q=0; q<10; ++q){
        uint4 v = *(const uint4*)(zl + n*88 + q*8);
        const uint_t* vu = (const uint_t*)&v;
        #pragma unroll
        for(int r=0; r<4; ++r){
            int ch = q*8 + r*2;
            float wA = (ch < 20) ? w0 : (ch < 40) ? w1 : (ch < 60) ? w2 : w3;
            float wB = (ch+1 < 20) ? w0 : (ch+1 < 40) ? w1 : (ch+1 < 60) ? w2 : w3;
            acc[ch]   = wA*bflo(vu[r]);
            acc[ch+1] = wB*bfhi(vu[r]);
        }
    }
    for(int i=0; i<dg; ++i){
        int s = el[i] & (NPG-1);
        float4 es_s = esl[s];
        float wa0 = expf(lrelu(es_s.x + edn.x));
        float wa1 = expf(lrelu(es_s.y + edn.y));
        float wa2 = expf(lrelu(es_s.z + edn.z));
        float wa3 = expf(lrelu(es_s.w + edn.w));
        den0 += wa0; den1 += wa1; den2 += wa2; den3 += wa3;
        #pragma unroll
        for(int q=0; q<10; ++q){
            uint4 v = *(const uint4*)(zl + s*88 + q*8);
            const uint_t* vu = (const uint_t*)&v;
            #pragma unroll
            for(int r=0; r<4; ++r){
                int ch = q*8 + r*2;
                float wA = (ch < 20) ? wa0 : (ch < 40) ? wa1 : (ch < 60) ? wa2 : wa3;
                float wB = (ch+1 < 20) ? wa0 : (ch+1 < 40) ? wa1 : (ch+1 < 60) ? wa2 : wa3;
                acc[ch]   += wA*bflo(vu[r]);
                acc[ch+1] += wB*bfhi(vu[r]);
            }
        }
    }
    float inv0 = 1.f/(den0 + 1e-16f);
    float inv1 = 1.f/(den1 + 1e-16f);
    float inv2 = 1.f/(den2 + 1e-16f);
    float inv3 = 1.f/(den3 + 1e-16f);
    const float* bb = bias + hg*80;
    uint_t* o = (uint_t*)out + (size_t)(base+n)*80 + hg*40;
    #pragma unroll
    for(int q=0; q<10; ++q){
        #pragma unroll
        for(int r=0; r<4; ++r){
            int ch = q*8 + r*2;
            float iA = (ch < 20) ? inv0 : (ch < 40) ? inv1 : (ch < 60) ? inv2 : inv3;
            float iB = (ch+1 < 20) ? inv0 : (ch+1 < 40) ? inv1 : (ch+1 < 60) ? inv2 : inv3;
            float v0 = fmaxf(acc[ch]*iA   + bb[ch],   0.f);
            float v1 = fmaxf(acc[ch+1]*iB + bb[ch+1], 0.f);
            o[q*4 + r] = (uint_t)f2bf(v0) | ((uint_t)f2bf(v1) << 16);
        }
    }
}

// ---------------- MFMA GEMM from prebuilt bf16 image; es/ed from last fragment ----------
template<int IN, int OUTC, int OUTIMG, bool ESED8>
__global__ __launch_bounds__(256) void k_gemm2(const ushort_t* __restrict__ Wimg,
                                               const ushort_t* __restrict__ A,
                                               ushort_t* __restrict__ C,
                                               float* __restrict__ oa,
                                               float* __restrict__ ob){
    constexpr int LDW = IN + 8;
    constexpr int NT = OUTIMG/16;
    constexpr int NC = OUTC/16;
    constexpr int KS = IN/32;
    constexpr int ELEMS = OUTIMG*LDW;
    __shared__ __align__(16) ushort_t Wt[ELEMS];
    int tid = threadIdx.x;
    int blk = xswz(blockIdx.x, N_NODES/64);
    int wave = tid >> 6, lane = tid & 63;
    int col16 = lane & 15;
    int kq = (lane >> 4) * 8;
    int row = blk*64 + wave*16 + col16;
    const ushort_t* Ar = A + (size_t)row*IN + kq;
    short8 afr[KS];
    #pragma unroll
    for(int ks=0; ks<KS; ++ks)
        afr[ks] = *reinterpret_cast<const short8*>(Ar + ks*32);
    for(int i = tid; i < ELEMS/8; i += 256)
        ((uint4*)Wt)[i] = ((const uint4*)Wimg)[i];
    __syncthreads();
    f32x4 acc[NT];
    #pragma unroll
    for(int c=0;c<NT;++c) acc[c] = (f32x4){0.f,0.f,0.f,0.f};
    #pragma unroll
    for(int ks=0; ks<KS; ++ks){
        #pragma unroll
        for(int c=0;c<NT;++c){
            short8 bf = *reinterpret_cast<const short8*>(&Wt[(c*16 + col16)*LDW + ks*32 + kq]);
            acc[c] = __builtin_amdgcn_mfma_f32_16x16x32_bf16(afr[ks], bf, acc[c], 0, 0, 0);
        }
    }
    int rbase = blk*64 + wave*16 + (lane >> 4)*4;
    #pragma unroll
    for(int c=0;c<NC;++c){
        #pragma unroll
        for(int r=0;r<4;++r){
            C[(size_t)(rbase + r)*OUTC + c*16 + col16] = f2bf(acc[c][r]);
        }
    }
    if(ESED8){
        #pragma unroll
        for(int r=0;r<4;++r){
            float v = acc[NT-1][r];
            if(col16 < 8) oa[(size_t)(rbase + r)*8 + col16] = v;
            else          ob[(size_t)(rbase + r)*8 + (col16 - 8)] = v;
        }
    } else {
        if(col16 == 0){
            #pragma unroll
            for(int r=0;r<4;++r) oa[rbase + r] = acc[NT-1][r];
        }
        if(col16 == 1){
            #pragma unroll
            for(int r=0;r<4;++r) ob[rbase + r] = acc[NT-1][r];
        }
    }
}

// ---------------- 1-head attention aggregate (wave per node), no-max softmax ----------------
// (REVERT of R10's attn1L: wave-per-node global-gather with readlane + unroll x4)
template<typename OutT, bool DOT>
__global__ void k_attn1(const int* __restrict__ deg, const int* __restrict__ ell,
                        const ushort_t* __restrict__ Z, const float* __restrict__ es,
                        const float* __restrict__ ed, const float* __restrict__ bias,
                        OutT* __restrict__ out,
                        const float* __restrict__ wa, const float* __restrict__ wb,
                        float* __restrict__ oa, float* __restrict__ ob){
    int blk = xswz(blockIdx.x, N_NODES/4);
    int gt = blk*blockDim.x + threadIdx.x;
    int n = gt >> 6;
    int l = threadIdx.x & 63;
    int dg = deg[n]; if(dg > MAXDEG) dg = MAXDEG;
    float edn = ed[n];
    float wself = expf(lrelu(es[n] + edn));
    int s_l = 0; float w_l = 0.f;
    if(l < dg){ s_l = ell[n*MAXDEG + l]; w_l = expf(lrelu(es[s_l] + edn)); }
    float den = w_l;
    for(int o=32;o>0;o>>=1) den += __shfl_xor(den,o);
    den += wself;
    const uint_t* Zu = (const uint_t*)Z;
    uint_t zn = Zu[(size_t)n*64 + l];
    float acc0 = wself*bflo(zn);
    float acc1 = wself*bfhi(zn);
    int i = 0;
    for(; i+4 <= dg; i += 4){
        int s0 = __builtin_amdgcn_readlane(s_l, i);
        int s1 = __builtin_amdgcn_readlane(s_l, i+1);
        int s2 = __builtin_amdgcn_readlane(s_l, i+2);
        int s3 = __builtin_amdgcn_readlane(s_l, i+3);
        uint_t z0 = Zu[(size_t)s0*64 + l];
        uint_t z1 = Zu[(size_t)s1*64 + l];
        uint_t z2 = Zu[(size_t)s2*64 + l];
        uint_t z3 = Zu[(size_t)s3*64 + l];
        float w0 = rdlanef(w_l, i);
        float w1 = rdlanef(w_l, i+1);
        float w2 = rdlanef(w_l, i+2);
        float w3 = rdlanef(w_l, i+3);
        acc0 += w0*bflo(z0) + w1*bflo(z1);
        acc1 += w0*bfhi(z0) + w1*bfhi(z1);
        acc0 += w2*bflo(z2) + w3*bflo(z3);
        acc1 += w2*bfhi(z2) + w3*bfhi(z3);
    }
    for(; i < dg; ++i){
        int s0 = __builtin_amdgcn_readlane(s_l, i);
        float w0 = rdlanef(w_l, i);
        uint_t z0 = Zu[(size_t)s0*64 + l];
        acc0 += w0*bflo(z0);
        acc1 += w0*bfhi(z0);
    }
    float inv = 1.f/(den + 1e-16f);
    float2 bb = ((const float2*)bias)[l];
    float r0 = fmaxf(acc0*inv + bb.x, 0.f);
    float r1 = fmaxf(acc1*inv + bb.y, 0.f);
    if(sizeof(OutT) == 2){
        ((uint_t*)out)[(size_t)n*64 + l] = (uint_t)f2bf(r0) | ((uint_t)f2bf(r1) << 16);
    } else {
        float2 rv; rv.x = r0; rv.y = r1;
        ((float2*)out)[(size_t)n*64 + l] = rv;
    }
    if(DOT){
        float2 a2 = ((const float2*)wa)[l];
        float2 b2 = ((const float2*)wb)[l];
        float pa = r0*a2.x + r1*a2.y;
        float pb = r0*b2.x + r1*b2.y;
        for(int o=32;o>0;o>>=1){ pa += __shfl_xor(pa,o); pb += __shfl_xor(pb,o); }
        if(l==0){ oa[n] = pa; ob[n] = pb; }
    }
}

// ---------------- pooling score ----------------
__global__ void k_score(const int* __restrict__ deg, const int* __restrict__ ell,
                        const float* __restrict__ yrel, const float* __restrict__ rroot,
                        const float* __restrict__ bpool, float* __restrict__ score){
    int blk = xswz(blockIdx.x, N_NODES/256);
    int n = blk*blockDim.x + threadIdx.x;
    int dg = deg[n]; if(dg > MAXDEG) dg = MAXDEG;
    float s = rroot[n] + bpool[0];
    const int* el = ell + n*MAXDEG;
    int i = 0;
    for(; i+4 <= dg; i += 4){
        float y0 = yrel[el[i]],   y1 = yrel[el[i+1]];
        float y2 = yrel[el[i+2]], y3 = yrel[el[i+3]];
        s += (y0 + y1) + (y2 + y3);
    }
    for(; i < dg; ++i) s += yrel[el[i]];
    score[n] = tanhf(s);
}

// ---------------- per-graph top-k: single-wave register bitonic + parallel pool ----------------
__global__ __launch_bounds__(512) void k_topk_pool(const float* __restrict__ score,
                                                   const ushort_t* __restrict__ H,
                                                   float* __restrict__ pooled,
                                                   float* __restrict__ perm_f,
                                                   float* __restrict__ sv,
                                                   float* __restrict__ batch_f){
    __shared__ int   sidx[KSEL];
    __shared__ float sval[KSEL];
    __shared__ float pmax[512];
    int g = xswz(blockIdx.x, NGRAPH);
    int base = g*NPG;
    int t = threadIdx.x;
    if(t < 64){
        int l = t;
        u64 v[8];
        #pragma unroll
        for(int r=0;r<8;++r){
            int i = r*64 + l;
            v[r] = comp_make(score[base + i], i);
        }
        #pragma unroll
        for(int kk=1; kk<=9; ++kk){
            int k = 1 << kk;
            #pragma unroll
            for(int jj=kk-1; jj>=0; --jj){
                int j = 1 << jj;
                if(j < 64){
                    bool lower = (l & j) == 0;
                    #pragma unroll
                    for(int r=0;r<8;++r){
                        int i = r*64 + l;
                        u64 p = shfl_xor_u64(v[r], j);
                        bool desc = (i & k) == 0;
                        u64 mx = v[r] > p ? v[r] : p;
                        u64 mn = v[r] > p ? p : v[r];
                        v[r] = (lower == desc) ? mx : mn;
                    }
                } else {
                    int jr = j >> 6;
                    #pragma unroll
                    for(int r=0;r<8;++r){
                        if((r & jr) == 0){
                            int rp = r | jr;
                            int i = r*64 + l;
                            bool desc = (i & k) == 0;
                            u64 a = v[r], b = v[rp];
                            u64 mx = a > b ? a : b;
                            u64 mn = a > b ? b : a;
                            v[r]  = desc ? mx : mn;
                            v[rp] = desc ? mn : mx;
                        }
                    }
                }
            }
        }
        #pragma unroll
        for(int r=0;r<4;++r){
            int i = r*64 + l;
            int idx = comp_idx(v[r]);
            float s = comp_score(v[r]);
            perm_f[g*KSEL + i]  = (float)(base + idx);
            sv[g*KSEL + i]      = s;
            batch_f[g*KSEL + i] = (float)g;
            sidx[i] = idx; sval[i] = s;
        }
    }
    __syncthreads();
    int c = t & 127, kc = t >> 7;
    float mx = -1e30f;
    for(int kk = kc*64; kk < kc*64 + 64; ++kk){
        mx = fmaxf(mx, bf2f(H[(size_t)(base + sidx[kk])*HID + c]) * sval[kk]);
    }
    pmax[t] = mx;
    __syncthreads();
    if(t < HID){
        pooled[g*HID + t] = fmaxf(fmaxf(pmax[t], pmax[t+128]),
                                  fmaxf(pmax[t+256], pmax[t+384]));
    }
}

extern "C" void kernel_launch(void* const* d_in, const int* in_sizes, int n_in,
                              void* d_out, int out_size, void* d_ws, size_t ws_size,
                              hipStream_t stream) {
    const int*   x       = (const int*)  d_in[0];
    const int*   eidx    = (const int*)  d_in[1];
    const float* W_a1    = (const float*)d_in[3];
    const float* asrc_a1 = (const float*)d_in[4];
    const float* adst_a1 = (const float*)d_in[5];
    const float* b_a1    = (const float*)d_in[6];
    const float* W_a2    = (const float*)d_in[7];
    const float* asrc_a2 = (const float*)d_in[8];
    const float* adst_a2 = (const float*)d_in[9];
    const float* b_a2    = (const float*)d_in[10];
    const float* W_b1    = (const float*)d_in[11];
    const float* asrc_b1 = (const float*)d_in[12];
    const float* adst_b1 = (const float*)d_in[13];
    const float* b_b1    = (const float*)d_in[14];
    const float* W_b2    = (const float*)d_in[15];
    const float* asrc_b2 = (const float*)d_in[16];
    const float* adst_b2 = (const float*)d_in[17];
    const float* b_b2    = (const float*)d_in[18];
    const float* w_rel   = (const float*)d_in[19];
    const float* w_root  = (const float*)d_in[20];
    const float* b_pool  = (const float*)d_in[21];

    const int* e_src = eidx;
    const int* e_dst = eidx + E_EDGES;

    char* ws = (char*)d_ws;
    size_t off = 0;
    auto alloc = [&](size_t bytes)->char*{
        char* p = ws + off;
        off += (bytes + 255) & ~(size_t)255;
        return p;
    };
    int*      deg    = (int*)     alloc((size_t)N_NODES*4);
    int*      ell    = (int*)     alloc((size_t)N_NODES*MAXDEG*4);
    ushort_t* z8     = (ushort_t*)alloc((size_t)N_NODES*D160*2);
    ushort_t* h8     = (ushort_t*)alloc((size_t)N_NODES*D160*2);
    ushort_t* zc     = (ushort_t*)alloc((size_t)N_NODES*HID*2);
    ushort_t* hmid   = (ushort_t*)alloc((size_t)N_NODES*HID*2);
    ushort_t* hfin   = (ushort_t*)alloc((size_t)N_NODES*HID*2);
    float*    es8    = (float*)   alloc((size_t)N_NODES*NHEADS*4);
    float*    ed8    = (float*)   alloc((size_t)N_NODES*NHEADS*4);
    float*    es1    = (float*)   alloc((size_t)N_NODES*4);
    float*    ed1    = (float*)   alloc((size_t)N_NODES*4);
    float*    yrel   = (float*)   alloc((size_t)N_NODES*4);
    float*    rroot  = (float*)   alloc((size_t)N_NODES*4);
    float*    score  = (float*)   alloc((size_t)N_NODES*4);
    ushort_t* Wbf    = (ushort_t*)alloc((size_t)NLBL*D160*2);
    float*    esT    = (float*)   alloc((size_t)NLBL*8*4);
    float*    edT    = (float*)   alloc((size_t)NLBL*8*4);
    ushort_t* imgA2  = (ushort_t*)alloc((size_t)IMG_A2_ELEMS*2);
    ushort_t* imgB1  = (ushort_t*)alloc((size_t)IMG_B1_ELEMS*2);
    ushort_t* imgB2  = (ushort_t*)alloc((size_t)IMG_A2_ELEMS*2);
    (void)ws_size; (void)n_in; (void)in_sizes; (void)out_size;

    float* out      = (float*)d_out;
    float* pooled   = out;
    float* perm_f   = out + NGRAPH*HID;
    float* sv       = perm_f + NGRAPH*KSEL;
    float* batch_f  = sv + NGRAPH*KSEL;

    k_prep<<<PB_TOT, 256, 0, stream>>>(W_a1, asrc_a1, adst_a1,
                                       W_a2, asrc_a2, adst_a2,
                                       W_b1, asrc_b1, adst_b1,
                                       W_b2, asrc_b2, adst_b2,
                                       deg, imgA2, imgB1, imgB2, Wbf, esT, edT);
    k_build_ell<<<E_EDGES/256, 256, 0, stream>>>(e_src, e_dst, deg, ell);

    // ---- GATNet A, conv1: fused table-attention ----
    k_attn8_a<<<N_NODES*NHEADS/256, 256, 0, stream>>>(x, deg, ell, Wbf, esT, edT, b_a1, h8);

    // ---- GATNet A, conv2 (160 -> 128) + es1/ed1 via extra image cols ----
    k_gemm2<D160, HID, 144, false><<<N_NODES/64, 256, 0, stream>>>(imgA2, h8, zc, es1, ed1);
    k_attn1<ushort_t, false><<<N_NODES/4, 256, 0, stream>>>(deg, ell, zc, es1, ed1, b_a2, hmid,
                                                            nullptr, nullptr, nullptr, nullptr);

    // ---- GATNet B, conv1 (128 -> 20x8) + es8/ed8 via extra image cols ----
    k_gemm2<HID, D160, 176, true><<<N_NODES/64, 256, 0, stream>>>(imgB1, hmid, z8, es8, ed8);
    k_attn8b<<<NGRAPH*2, 512, 0, stream>>>(deg, ell, z8, es8, ed8, b_b1, h8);

    // ---- GATNet B, conv2 (160 -> 128) + es1/ed1 via extra image cols ----
    k_gemm2<D160, HID, 144, false><<<N_NODES/64, 256, 0, stream>>>(imgB2, h8, zc, es1, ed1);
    // final attention (bf16 out) + fused pooling dots (yrel, rroot)
    k_attn1<ushort_t, true><<<N_NODES/4, 256, 0, stream>>>(deg, ell, zc, es1, ed1, b_b2, hfin,
                                                           w_rel, w_root, yrel, rroot);

    // ---- SAGPooling ----
    k_score<<<N_NODES/256, 256, 0, stream>>>(deg, ell, yrel, rroot, b_pool, score);
    k_topk_pool<<<NGRAPH, NPG, 0, stream>>>(score, hfin, pooled, perm_f, sv, batch_f);
}